// Round 12
// baseline (1054.346 us; speedup 1.0000x reference)
//
#include <hip/hip_runtime.h>
#include <hip/hip_bf16.h>

typedef float f32x4 __attribute__((ext_vector_type(4)));
typedef short short8 __attribute__((ext_vector_type(8)));   // 8 bf16 = 16 B
typedef short short4v __attribute__((ext_vector_type(4)));  // 4 bf16 = 8 B

__device__ __forceinline__ short f2b(float x) {
    union { __hip_bfloat16 b; short s; } u;
    u.b = __float2bfloat16(x);   // round-to-nearest-even
    return u.s;
}

// async global->LDS, 16 B per lane; LDS dest is wave-uniform base + lane*16.
__device__ __forceinline__ void gload16(const void* g, void* l) {
    __builtin_amdgcn_global_load_lds(
        (const __attribute__((address_space(1))) unsigned int*)g,
        (__attribute__((address_space(3))) unsigned int*)l, 16, 0, 0);
}

// ---------------------------------------------------------------------------
// Converter 1: A sources fp32 -> Aws[row][kglob] bf16 (kglob = s*2048+k).
// ---------------------------------------------------------------------------
__global__ __launch_bounds__(256)
void conv_a(const float* __restrict__ x0, const float* __restrict__ x1,
            const float* __restrict__ x2, unsigned short* __restrict__ Aws)
{
    const long i = (long)blockIdx.x * 256 + threadIdx.x;   // unit = 8 elems
    const long per_src = (long)4096 * 2048 / 8;
    const int  s = (int)(i / per_src);
    const long e0 = (i % per_src) * 8;
    const int  row = (int)(e0 >> 11), kl = (int)(e0 & 2047);
    const float* src = (s == 0) ? x0 : (s == 1) ? x1 : x2;
    const f32x4 v0 = *(const f32x4*)(src + e0);
    const f32x4 v1 = *(const f32x4*)(src + e0 + 4);
    short8 p;
    #pragma unroll
    for (int j = 0; j < 4; ++j) { p[j] = f2b(v0[j]); p[4 + j] = f2b(v1[j]); }
    *(short8*)&Aws[(long)row * 6144 + s * 2048 + kl] = p;
}

// ---------------------------------------------------------------------------
// Converter 2: weights fp32 -> FRAGMENT-MAJOR bf16 layout:
//   Bws[((e16*96 + t)*1024) + kh*512 + q*128 + l15*8 + j]
//     = W(effcol = e16*16 + l15, kglob = t*64 + kh*32 + q*8 + j)
// where effcol = gate*2048 + hcol (gate-major), kglob = s*2048 + k.
// A wave's B-fragment load is then base + lane*16B: fully coalesced 1 KB.
// ---------------------------------------------------------------------------
__global__ __launch_bounds__(256)
void conv_b(const float* __restrict__ Wk, const float* __restrict__ Wr,
            const float* __restrict__ Wl, unsigned short* __restrict__ Bws)
{
    __shared__ float lt[64][65];
    const int bid = (int)blockIdx.x;
    const int s   = bid >> 12;            // 3 sources
    const int r   = bid & 4095;
    const int kbase = (r >> 7) * 64;      // 32 k-tiles
    const int ebase = (r & 127) * 64;     // 128 effcol-tiles
    const float* W = (s == 0) ? Wk : (s == 1) ? Wr : Wl;
    const int tr = threadIdx.x >> 4, tc = threadIdx.x & 15;

    #pragma unroll
    for (int p = 0; p < 4; ++p) {
        const int kr = p * 16 + tr;
        const f32x4 v = *(const f32x4*)&W[(long)(kbase + kr) * 8192 + ebase + tc * 4];
        #pragma unroll
        for (int j = 0; j < 4; ++j) lt[kr][tc * 4 + j] = v[j];
    }
    __syncthreads();

    // Write phase: thread tid covers one (e16sub, kh, q, lo3) cell = 2 x 16 B.
    const int tid = threadIdx.x;
    const int e16sub = tid >> 6;          // 0..3
    const int r6 = tid & 63;
    const int kh = r6 >> 5, r5 = r6 & 31;
    const int q  = r5 >> 3, lo3 = r5 & 7;
    const long tbase =
        ((long)((ebase >> 4) + e16sub) * 96 + (long)s * 32 + (kbase >> 6)) * 1024
        + kh * 512 + q * 128 + lo3 * 16;
    #pragma unroll
    for (int d = 0; d < 2; ++d) {
        const int l15 = lo3 * 2 + d;
        short8 pv;
        #pragma unroll
        for (int j = 0; j < 8; ++j)
            pv[j] = f2b(lt[kh * 32 + q * 8 + j][e16sub * 16 + l15]);
        *(short8*)&Bws[tbase + d * 8] = pv;
    }
}

// ---------------------------------------------------------------------------
// 256x256eff GEMM, B-direct v2 (coalesced): A staged in LDS (dbuf 2x32 KB,
// DMA, swizzle conflict-free); B fragments loaded global->VGPR from the
// fragment-major layout: one coalesced 1KB dwordx4 per (gate,kh), 8/tile,
// double-banked one tile ahead (b0/b1; reg-dep waits auto-inserted by the
// compiler; explicit counted vmcnt(8) only guards the A-DMA). LDS carries A
// only (~1280 cyc/tile). setprio kept (R10: removing it cost 6pt MfmaUtil).
// One barrier/tile. Per-lane fragment content and MFMA order bit-identical
// to rounds 5-11 -> absmax 1.733e-2 expected exactly.
// ---------------------------------------------------------------------------
__global__ __launch_bounds__(512, 2)
void vlstm_gemm_bf(const unsigned short* __restrict__ Aws,
                   const unsigned short* __restrict__ Bws,
                   const float* __restrict__ c_tm1,
                   const float* __restrict__ bias,
                   float* __restrict__ out)
{
    __shared__ __align__(16) unsigned short As[2][256][64];   // 64 KB

    const int tid  = threadIdx.x;
    const int w    = tid >> 6, lane = tid & 63;
    const int wm   = w >> 2,  wn   = w & 3;     // 2 x 4 wave grid
    const int l15  = lane & 15, q = lane >> 4;
    const int lrow = lane >> 3;                 // A staging: row within 8-row chunk
    const int lsw  = (lane & 7) ^ lrow;         // A staging: swizzled source octet
    const int oq   = q ^ (l15 & 7);             // A read: swizzled octet base

    const int bid = (int)blockIdx.x;
    const int swz = (bid & 7) * 64 + (bid >> 3);    // XCD-bijective (512 % 8 == 0)
    const int bm  = swz >> 5, bn = swz & 31;        // 16 x 32
    const int row0 = bm * 256, c0 = bn * 64;        // c0 in hcols

    const long a_base = (long)(row0 + w * 16 + lrow) * 6144 + lsw * 8;

    // B fragment-major bases: e16 = g*128 + (c0>>4) + wn; per-lane +lane*8.
    const unsigned short* bpg[4];
    #pragma unroll
    for (int g = 0; g < 4; ++g)
        bpg[g] = Bws + ((long)(g * 128 + (c0 >> 4) + wn) * (96 * 1024) + lane * 8);

    f32x4 acc[8][4];            // [mi 0..7][gate]
    #pragma unroll
    for (int mi = 0; mi < 8; ++mi)
        #pragma unroll
        for (int g = 0; g < 4; ++g)
            acc[mi][g] = (f32x4){0.f, 0.f, 0.f, 0.f};

    short8 afr[4][2];           // current mh-half: [mi][kh]
    short8 b0[4][2], b1[4][2];  // B fragment banks: [gate][kh]

#define STAGE_A(buf_, t_, h_) do { _Pragma("unroll")                             \
    for (int j_ = 0; j_ < 2; ++j_)                                               \
        gload16(Aws + a_base + (long)((h_) * 128 + j_ * 8) * 6144                \
                    + (long)(t_) * 64,                                           \
                &As[buf_][(h_) * 128 + w * 16 + j_ * 8][0]); } while (0)

#define BLOADS(bank_, t_) do { _Pragma("unroll")                                 \
    for (int g_ = 0; g_ < 4; ++g_) {                                             \
        bank_[g_][0] = *(const short8*)(bpg[g_] + (long)(t_) * 1024);            \
        bank_[g_][1] = *(const short8*)(bpg[g_] + (long)(t_) * 1024 + 512);      \
    } } while (0)

#define LOAD_AFR(cur_, mh_) do { _Pragma("unroll")                               \
    for (int mi_ = 0; mi_ < 4; ++mi_) { _Pragma("unroll")                        \
        for (int kh_ = 0; kh_ < 2; ++kh_)                                        \
            afr[mi_][kh_] = *(const short8*)                                     \
                &As[cur_][wm * 128 + (mh_) * 64 + mi_ * 16 + l15]                \
                         [(oq ^ (kh_ << 2)) * 8]; } } while (0)

#define MFMA_Q(bank_, mh_, nlo_) do {                                            \
    __builtin_amdgcn_s_setprio(1);                                               \
    _Pragma("unroll")                                                            \
    for (int kh_ = 0; kh_ < 2; ++kh_) { _Pragma("unroll")                        \
        for (int mi_ = 0; mi_ < 4; ++mi_) { _Pragma("unroll")                    \
            for (int g_ = 0; g_ < 2; ++g_)                                       \
                acc[(mh_) * 4 + mi_][(nlo_) + g_] =                              \
                    __builtin_amdgcn_mfma_f32_16x16x32_bf16(                     \
                        afr[mi_][kh_], bank_[(nlo_) + g_][kh_],                  \
                        acc[(mh_) * 4 + mi_][(nlo_) + g_], 0, 0, 0); } }         \
    __builtin_amdgcn_s_setprio(0); } while (0)

// raw s_barrier is NOT a compiler memory fence -> pin both sides (rule 18/21).
#define BARRIER() do { __builtin_amdgcn_sched_barrier(0);                        \
    __builtin_amdgcn_s_barrier();                                                \
    __builtin_amdgcn_sched_barrier(0); } while (0)

// One K-tile: A frags from LDS (swizzled), B frags from cur_ bank; stage
// A(t+1) DMA then issue B(t+1) coalesced loads into nxt_ bank; counted
// vmcnt(8) at boundary waits only the 4 A-DMAs (8 newest = B loads fly on).
#define TILE_BODY(cur_, nxt_, t_) do {                                           \
    const int bufA_ = (t_) & 1;                                                  \
    LOAD_AFR(bufA_, 0);                                                          \
    if ((t_) + 1 < 96) {                                                         \
        STAGE_A(bufA_ ^ 1, (t_) + 1, 0);                                         \
        STAGE_A(bufA_ ^ 1, (t_) + 1, 1);                                         \
        BLOADS(nxt_, (t_) + 1);                                                  \
    }                                                                            \
    MFMA_Q(cur_, 0, 0);                                                          \
    MFMA_Q(cur_, 0, 2);                                                          \
    LOAD_AFR(bufA_, 1);                                                          \
    MFMA_Q(cur_, 1, 0);                                                          \
    MFMA_Q(cur_, 1, 2);                                                          \
    if ((t_) < 95) asm volatile("s_waitcnt vmcnt(8)" ::: "memory");              \
    else           asm volatile("s_waitcnt vmcnt(0)" ::: "memory");              \
    BARRIER(); } while (0)

    // Prologue: stage A(0) via DMA, load B(0) fragments, drain, barrier.
    STAGE_A(0, 0, 0);
    STAGE_A(0, 0, 1);
    BLOADS(b0, 0);
    asm volatile("s_waitcnt vmcnt(0)" ::: "memory");
    BARRIER();

    for (int t2 = 0; t2 < 96; t2 += 2) {   // 96 tiles, banks swap each tile
        TILE_BODY(b0, b1, t2);
        TILE_BODY(b1, b0, t2 + 1);
    }

#undef STAGE_A
#undef BLOADS
#undef LOAD_AFR
#undef MFMA_Q
#undef BARRIER
#undef TILE_BODY

    // Epilogue: C/D layout col = l15, row = q*4 + rr (m89/m91 HW-verified).
    {
        const int col = c0 + wn * 16 + l15;
        const float bi  = bias[col];
        const float bf_ = bias[2048 + col];
        const float bc  = bias[4096 + col];
        const float bo  = bias[6144 + col];
        #pragma unroll
        for (int mi = 0; mi < 8; ++mi) {
            const int rbase = row0 + wm * 128 + mi * 16 + q * 4;
            #pragma unroll
            for (int rr = 0; rr < 4; ++rr) {
                const int row = rbase + rr;
                const float xi = acc[mi][0][rr] + bi;
                const float xf = acc[mi][1][rr] + bf_;
                const float xc = acc[mi][2][rr] + bc;
                const float xo = acc[mi][3][rr] + bo;
                const float ig = __builtin_amdgcn_fmed3f(0.2f * xi + 0.5f, 0.f, 1.f);
                const float fg = __builtin_amdgcn_fmed3f(0.2f * xf + 0.5f, 0.f, 1.f);
                const float og = __builtin_amdgcn_fmed3f(0.2f * xo + 0.5f, 0.f, 1.f);
                const float cp = c_tm1[(long)row * 2048 + col];
                const float cc = fg * cp + ig * tanhf(xc);
                out[(long)row * 2048 + col] = og * tanhf(cc);
            }
        }
    }
}

// ---------------------------------------------------------------------------
// Legacy fallback (round-4 kernel, verbatim): only if ws_size is too small.
// ---------------------------------------------------------------------------
__global__ __launch_bounds__(256, 2)
void vlstm_fused_legacy(const float* __restrict__ xin, const float* __restrict__ h_tm1,
                        const float* __restrict__ c_tm1, const float* __restrict__ z_tm1,
                        const float* __restrict__ Wk, const float* __restrict__ Wr,
                        const float* __restrict__ Wl, const float* __restrict__ bias,
                        float* __restrict__ out)
{
    __shared__ __align__(16) unsigned short Alds[2][128][40];
    __shared__ __align__(16) unsigned short Blds[2][256][40];

    const int tid  = threadIdx.x;
    const int wave = tid >> 6, lane = tid & 63;
    const int wr = wave >> 1, wc = wave & 1;
    const int l15 = lane & 15, q = lane >> 4;

    const int bid = (int)blockIdx.x;
    const int swz = (bid & 7) * 128 + (bid >> 3);
    const int bm = swz >> 5, bn = swz & 31;
    const int row0 = bm * 128, col0 = bn * 64;

    const int arow = tid >> 1, kh = tid & 1;
    const long bg_off = (long)(tid >> 6) * 2048 + col0 + (tid & 63);

    f32x4 acc[4][4][2];
    #pragma unroll
    for (int g = 0; g < 4; ++g)
        #pragma unroll
        for (int mi = 0; mi < 4; ++mi)
            #pragma unroll
            for (int ni = 0; ni < 2; ++ni)
                acc[g][mi][ni] = (f32x4){0.f, 0.f, 0.f, 0.f};

    f32x4 sa[4];
    float sb[32];

#define DO_LOADS_L(kn_) do {                                                    \
    const int s_  = (kn_) >> 6;                                                 \
    const int kl_ = ((kn_) & 63) << 5;                                          \
    const float* Ap_ = (s_ == 0) ? xin : (s_ == 1) ? h_tm1 : z_tm1;             \
    const float* Bp_ = (s_ == 0) ? Wk  : (s_ == 1) ? Wr    : Wl;                \
    const float* ap_ = Ap_ + (long)(row0 + arow) * 2048 + kl_ + kh * 16;        \
    _Pragma("unroll")                                                           \
    for (int i_ = 0; i_ < 4; ++i_) sa[i_] = ((const f32x4*)ap_)[i_];            \
    const float* bp_ = Bp_ + (long)kl_ * 8192 + bg_off;                         \
    _Pragma("unroll")                                                           \
    for (int kk_ = 0; kk_ < 32; ++kk_) sb[kk_] = bp_[(long)kk_ * 8192];         \
} while (0)

#define DO_STORE_L(buf_) do {                                                   \
    short8 p0_, p1_;                                                            \
    _Pragma("unroll")                                                           \
    for (int j_ = 0; j_ < 4; ++j_) {                                            \
        p0_[j_] = f2b(sa[0][j_]); p0_[4 + j_] = f2b(sa[1][j_]);                 \
        p1_[j_] = f2b(sa[2][j_]); p1_[4 + j_] = f2b(sa[3][j_]);                 \
    }                                                                           \
    *(short8*)&Alds[buf_][arow][kh * 16]     = p0_;                             \
    *(short8*)&Alds[buf_][arow][kh * 16 + 8] = p1_;                             \
    _Pragma("unroll")                                                           \
    for (int ks_ = 0; ks_ < 4; ++ks_) {                                         \
        short8 pb_;                                                             \
        _Pragma("unroll")                                                       \
        for (int j_ = 0; j_ < 8; ++j_) pb_[j_] = f2b(sb[ks_ * 8 + j_]);         \
        *(short8*)&Blds[buf_][tid][ks_ * 8] = pb_;                              \
    }                                                                           \
} while (0)

    DO_LOADS_L(0);
    DO_STORE_L(0);
    __syncthreads();

    for (int kt = 0; kt < 192; ++kt) {
        const int cur = kt & 1;
        if (kt + 1 < 192) DO_LOADS_L(kt + 1);

        short8 afr[4];
        #pragma unroll
        for (int mi = 0; mi < 4; ++mi)
            afr[mi] = *(const short8*)&Alds[cur][wr * 64 + mi * 16 + l15][q * 8];

        short8 bfr[4][2];
        #pragma unroll
        for (int g = 0; g < 4; ++g)
            #pragma unroll
            for (int ni = 0; ni < 2; ++ni)
                bfr[g][ni] = *(const short8*)
                    &Blds[cur][g * 64 + wc * 32 + ni * 16 + l15][q * 8];

        #pragma unroll
        for (int g = 0; g < 4; ++g)
            #pragma unroll
            for (int ni = 0; ni < 2; ++ni)
                #pragma unroll
                for (int mi = 0; mi < 4; ++mi)
                    acc[g][mi][ni] = __builtin_amdgcn_mfma_f32_16x16x32_bf16(
                        afr[mi], bfr[g][ni], acc[g][mi][ni], 0, 0, 0);

        if (kt + 1 < 192) DO_STORE_L(cur ^ 1);
        __syncthreads();
    }

#undef DO_LOADS_L
#undef DO_STORE_L

    #pragma unroll
    for (int ni = 0; ni < 2; ++ni) {
        const int col = col0 + wc * 32 + ni * 16 + l15;
        const float bi  = bias[col];
        const float bf_ = bias[2048 + col];
        const float bc  = bias[4096 + col];
        const float bo  = bias[6144 + col];
        #pragma unroll
        for (int mi = 0; mi < 4; ++mi) {
            const int rbase = row0 + wr * 64 + mi * 16 + q * 4;
            #pragma unroll
            for (int rr = 0; rr < 4; ++rr) {
                const int row = rbase + rr;
                const float xi = acc[0][mi][ni][rr] + bi;
                const float xf = acc[1][mi][ni][rr] + bf_;
                const float xc = acc[2][mi][ni][rr] + bc;
                const float xo = acc[3][mi][ni][rr] + bo;
                const float ig = __builtin_amdgcn_fmed3f(0.2f * xi + 0.5f, 0.f, 1.f);
                const float fg = __builtin_amdgcn_fmed3f(0.2f * xf + 0.5f, 0.f, 1.f);
                const float og = __builtin_amdgcn_fmed3f(0.2f * xo + 0.5f, 0.f, 1.f);
                const float cp = c_tm1[(long)row * 2048 + col];
                const float cc = fg * cp + ig * tanhf(xc);
                out[(long)row * 2048 + col] = og * tanhf(cc);
            }
        }
    }
}

extern "C" void kernel_launch(void* const* d_in, const int* in_sizes, int n_in,
                              void* d_out, int out_size, void* d_ws, size_t ws_size,
                              hipStream_t stream) {
    const float* xin  = (const float*)d_in[0];
    const float* h1   = (const float*)d_in[1];
    const float* c1   = (const float*)d_in[2];
    const float* z1   = (const float*)d_in[3];
    const float* Wk   = (const float*)d_in[4];
    const float* Wr   = (const float*)d_in[5];
    const float* Wl   = (const float*)d_in[6];
    const float* bias = (const float*)d_in[7];
    float* out = (float*)d_out;
    (void)in_sizes; (void)n_in; (void)out_size;

    const size_t a_elems = (size_t)4096 * 6144;
    const size_t b_elems = (size_t)8192 * 6144;
    const size_t need = (a_elems + b_elems) * 2;       // ~151 MB

    if (ws_size >= need) {
        unsigned short* Aws = (unsigned short*)d_ws;
        unsigned short* Bws = Aws + a_elems;
        conv_a<<<dim3(12288), dim3(256), 0, stream>>>(xin, h1, z1, Aws);
        conv_b<<<dim3(12288), dim3(256), 0, stream>>>(Wk, Wr, Wl, Bws);
        // grid: 16 m-blocks x 32 hcol-blocks = 512
        vlstm_gemm_bf<<<dim3(512), dim3(512), 0, stream>>>(Aws, Bws, c1, bias, out);
    } else {
        vlstm_fused_legacy<<<dim3(1024), dim3(256), 0, stream>>>(
            xin, h1, c1, z1, Wk, Wr, Wl, bias, out);
    }
}

// Round 13
// 497.645 us; speedup vs baseline: 2.1187x; 2.1187x over previous
//
#include <hip/hip_runtime.h>
#include <hip/hip_bf16.h>

typedef float f32x4 __attribute__((ext_vector_type(4)));
typedef short short8 __attribute__((ext_vector_type(8)));   // 8 bf16 = 16 B
typedef short short4v __attribute__((ext_vector_type(4)));  // 4 bf16 = 8 B

__device__ __forceinline__ short f2b(float x) {
    union { __hip_bfloat16 b; short s; } u;
    u.b = __float2bfloat16(x);   // round-to-nearest-even
    return u.s;
}

// async global->LDS, 16 B per lane; LDS dest is wave-uniform base + lane*16.
__device__ __forceinline__ void gload16(const void* g, void* l) {
    __builtin_amdgcn_global_load_lds(
        (const __attribute__((address_space(1))) unsigned int*)g,
        (__attribute__((address_space(3))) unsigned int*)l, 16, 0, 0);
}

// ---------------------------------------------------------------------------
// Converter 1: A sources fp32 -> Aws[row][kglob] bf16 (kglob = s*2048+k).
// ---------------------------------------------------------------------------
__global__ __launch_bounds__(256)
void conv_a(const float* __restrict__ x0, const float* __restrict__ x1,
            const float* __restrict__ x2, unsigned short* __restrict__ Aws)
{
    const long i = (long)blockIdx.x * 256 + threadIdx.x;   // unit = 8 elems
    const long per_src = (long)4096 * 2048 / 8;
    const int  s = (int)(i / per_src);
    const long e0 = (i % per_src) * 8;
    const int  row = (int)(e0 >> 11), kl = (int)(e0 & 2047);
    const float* src = (s == 0) ? x0 : (s == 1) ? x1 : x2;
    const f32x4 v0 = *(const f32x4*)(src + e0);
    const f32x4 v1 = *(const f32x4*)(src + e0 + 4);
    short8 p;
    #pragma unroll
    for (int j = 0; j < 4; ++j) { p[j] = f2b(v0[j]); p[4 + j] = f2b(v1[j]); }
    *(short8*)&Aws[(long)row * 6144 + s * 2048 + kl] = p;
}

// ---------------------------------------------------------------------------
// Converter 2: weights fp32 -> Bws[effcol][kglob] bf16 (transposed),
// effcol = gate*2048 + hcol.
// ---------------------------------------------------------------------------
__global__ __launch_bounds__(256)
void conv_b(const float* __restrict__ Wk, const float* __restrict__ Wr,
            const float* __restrict__ Wl, unsigned short* __restrict__ Bws)
{
    __shared__ float lt[64][65];
    const int bid = (int)blockIdx.x;
    const int s   = bid >> 12;
    const int r   = bid & 4095;
    const int kbase = (r >> 7) * 64;
    const int ebase = (r & 127) * 64;
    const float* W = (s == 0) ? Wk : (s == 1) ? Wr : Wl;
    const int tr = threadIdx.x >> 4, tc = threadIdx.x & 15;

    #pragma unroll
    for (int p = 0; p < 4; ++p) {
        const int kr = p * 16 + tr;
        const f32x4 v = *(const f32x4*)&W[(long)(kbase + kr) * 8192 + ebase + tc * 4];
        #pragma unroll
        for (int j = 0; j < 4; ++j) lt[kr][tc * 4 + j] = v[j];
    }
    __syncthreads();
    #pragma unroll
    for (int p = 0; p < 4; ++p) {
        const int er = p * 16 + tr;
        const int k4 = tc * 4;
        short4v qv;
        #pragma unroll
        for (int j = 0; j < 4; ++j) qv[j] = f2b(lt[k4 + j][er]);
        *(short4v*)&Bws[(long)(ebase + er) * 6144 + (long)s * 2048 + kbase + k4] = qv;
    }
}

// ---------------------------------------------------------------------------
// 256x256eff GEMM, free-slip schedule (round-9 optimum, restored verbatim):
// ONE barrier per K-tile. A double-buffered (2x32 KB), B TRIPLE-buffered
// (3x32 KB): no staging write in tile t targets a buffer read in tile t;
// cross-tile overwrites are ordered by the boundary barrier. Waves slip:
// one wave's MFMA cluster overlaps another's ds_reads. setprio kept (R10
// A/B: removing it costs 6pt MfmaUtil). Counted vmcnt(4) per boundary
// (vmcnt(0) only t>=94). B in LDS (R11/R12 A/B: both B-direct variants
// regress -42%/-134% -- scattered lines / register spill).
// MFMA order per acc element identical to rounds 5-12 -> absmax 1.733e-2.
// ---------------------------------------------------------------------------
__global__ __launch_bounds__(512, 2)
void vlstm_gemm256(const unsigned short* __restrict__ Aws,
                   const unsigned short* __restrict__ Bws,
                   const float* __restrict__ c_tm1,
                   const float* __restrict__ bias,
                   float* __restrict__ out)
{
    __shared__ __align__(16) unsigned short As[2][256][64];   // 64 KB
    __shared__ __align__(16) unsigned short Bs[3][256][64];   // 96 KB

    const int tid  = threadIdx.x;
    const int w    = tid >> 6, lane = tid & 63;
    const int wm   = w >> 2,  wn   = w & 3;     // 2 x 4 wave grid
    const int l15  = lane & 15, q = lane >> 4;
    const int lrow = lane >> 3;                 // staging: row within 8-row chunk
    const int lsw  = (lane & 7) ^ lrow;         // staging: swizzled source octet
    const int oq   = q ^ (l15 & 7);             // read: swizzled octet base

    const int bid = (int)blockIdx.x;
    const int swz = (bid & 7) * 64 + (bid >> 3);    // XCD-bijective (512 % 8 == 0)
    const int bm  = swz >> 5, bn = swz & 31;        // 16 x 32
    const int row0 = bm * 256, c0 = bn * 64;        // c0 in hcols

    const long a_base = (long)(row0 + w * 16 + lrow) * 6144 + lsw * 8;

    f32x4 acc[8][4];            // [mi 0..7][gate]
    #pragma unroll
    for (int mi = 0; mi < 8; ++mi)
        #pragma unroll
        for (int g = 0; g < 4; ++g)
            acc[mi][g] = (f32x4){0.f, 0.f, 0.f, 0.f};

    short8 afr[4][2];           // current mh-half: [mi_][kh]
    short8 bfr[4][2];           // all 4 gates resident: [ni][kh]

#define STAGE_A(buf_, t_, h_) do { _Pragma("unroll")                             \
    for (int j_ = 0; j_ < 2; ++j_)                                               \
        gload16(Aws + a_base + (long)((h_) * 128 + j_ * 8) * 6144                \
                    + (long)(t_) * 64,                                           \
                &As[buf_][(h_) * 128 + w * 16 + j_ * 8][0]); } while (0)

#define STAGE_B(buf_, t_, h_) do { _Pragma("unroll")                             \
    for (int j_ = 0; j_ < 2; ++j_) {                                             \
        const int e0_ = (h_) * 128 + w * 16 + j_ * 8;                            \
        const int grow_ = ((e0_ >> 4) & 3) * 2048 + c0 + (e0_ >> 6) * 16         \
                          + (e0_ & 8) + lrow;                                    \
        gload16(Bws + (long)grow_ * 6144 + lsw * 8 + (long)(t_) * 64,            \
                &Bs[buf_][e0_][0]); } } while (0)

#define LOAD_AFR(cur_, mh_) do { _Pragma("unroll")                               \
    for (int mi_ = 0; mi_ < 4; ++mi_) { _Pragma("unroll")                        \
        for (int kh_ = 0; kh_ < 2; ++kh_)                                        \
            afr[mi_][kh_] = *(const short8*)                                     \
                &As[cur_][wm * 128 + (mh_) * 64 + mi_ * 16 + l15]                \
                         [(oq ^ (kh_ << 2)) * 8]; } } while (0)

#define LOAD_BFR(cur_, nlo_) do { _Pragma("unroll")                              \
    for (int g_ = 0; g_ < 2; ++g_) { _Pragma("unroll")                           \
        for (int kh_ = 0; kh_ < 2; ++kh_)                                        \
            bfr[(nlo_) + g_][kh_] = *(const short8*)                             \
                &Bs[cur_][wn * 64 + ((nlo_) + g_) * 16 + l15]                    \
                         [(oq ^ (kh_ << 2)) * 8]; } } while (0)

#define MFMA_Q(mh_, nlo_) do {                                                   \
    __builtin_amdgcn_s_setprio(1);                                               \
    _Pragma("unroll")                                                            \
    for (int kh_ = 0; kh_ < 2; ++kh_) { _Pragma("unroll")                        \
        for (int mi_ = 0; mi_ < 4; ++mi_) { _Pragma("unroll")                    \
            for (int g_ = 0; g_ < 2; ++g_)                                       \
                acc[(mh_) * 4 + mi_][(nlo_) + g_] =                              \
                    __builtin_amdgcn_mfma_f32_16x16x32_bf16(                     \
                        afr[mi_][kh_], bfr[(nlo_) + g_][kh_],                    \
                        acc[(mh_) * 4 + mi_][(nlo_) + g_], 0, 0, 0); } }         \
    __builtin_amdgcn_s_setprio(0); } while (0)

// raw s_barrier is NOT a compiler memory fence -> pin both sides (rule 18/21).
#define BARRIER() do { __builtin_amdgcn_sched_barrier(0);                        \
    __builtin_amdgcn_s_barrier();                                                \
    __builtin_amdgcn_sched_barrier(0); } while (0)

    // Prologue: stage A(0)->bufA0, B(0)->bufB0, B(1)->bufB1.
    // vmcnt(4): A(0)+B(0) (oldest 8) arrived; B(1) (4) stays in flight.
    STAGE_A(0, 0, 0); STAGE_A(0, 0, 1);
    STAGE_B(0, 0, 0); STAGE_B(0, 0, 1);
    STAGE_B(1, 1, 0); STAGE_B(1, 1, 1);
    asm volatile("s_waitcnt vmcnt(4)" ::: "memory");
    BARRIER();

    int bB = 0;   // t % 3, maintained incrementally (wave-uniform)
    for (int t = 0; t < 96; ++t) {
        const int bA = t & 1, bAn = bA ^ 1;
        const int bBs = bB ? bB - 1 : 2;        // (t+2) % 3
        // free-slip tile body: no intra-tile barriers; source order keeps the
        // read clusters interleaved with MFMA clusters for the scheduler.
        LOAD_AFR(bA, 0);
        LOAD_BFR(bB, 0);
        if (t + 1 < 96) STAGE_A(bAn, t + 1, 0);
        MFMA_Q(0, 0);
        LOAD_BFR(bB, 2);
        if (t + 1 < 96) STAGE_A(bAn, t + 1, 1);
        MFMA_Q(0, 2);
        LOAD_AFR(bA, 1);
        if (t + 2 < 96) STAGE_B(bBs, t + 2, 0);
        MFMA_Q(1, 0);
        if (t + 2 < 96) STAGE_B(bBs, t + 2, 1);
        MFMA_Q(1, 2);
        // boundary: counted vmcnt guards next tile's operands; single barrier.
        if (t < 94) asm volatile("s_waitcnt vmcnt(4)" ::: "memory");
        else        asm volatile("s_waitcnt vmcnt(0)" ::: "memory");
        BARRIER();
        bB = (bB == 2) ? 0 : bB + 1;
    }

#undef STAGE_A
#undef STAGE_B
#undef LOAD_AFR
#undef LOAD_BFR
#undef MFMA_Q
#undef BARRIER

    // Epilogue: C/D layout col = l15, row = q*4 + rr (m89/m91 HW-verified).
    {
        const int col = c0 + wn * 16 + l15;
        const float bi  = bias[col];
        const float bf_ = bias[2048 + col];
        const float bc  = bias[4096 + col];
        const float bo  = bias[6144 + col];
        #pragma unroll
        for (int mi = 0; mi < 8; ++mi) {
            const int rbase = row0 + wm * 128 + mi * 16 + q * 4;
            #pragma unroll
            for (int rr = 0; rr < 4; ++rr) {
                const int row = rbase + rr;
                const float xi = acc[mi][0][rr] + bi;
                const float xf = acc[mi][1][rr] + bf_;
                const float xc = acc[mi][2][rr] + bc;
                const float xo = acc[mi][3][rr] + bo;
                const float ig = __builtin_amdgcn_fmed3f(0.2f * xi + 0.5f, 0.f, 1.f);
                const float fg = __builtin_amdgcn_fmed3f(0.2f * xf + 0.5f, 0.f, 1.f);
                const float og = __builtin_amdgcn_fmed3f(0.2f * xo + 0.5f, 0.f, 1.f);
                const float cp = c_tm1[(long)row * 2048 + col];
                const float cc = fg * cp + ig * tanhf(xc);
                out[(long)row * 2048 + col] = og * tanhf(cc);
            }
        }
    }
}

// ---------------------------------------------------------------------------
// Legacy fallback (round-4 kernel, verbatim): only if ws_size is too small.
// ---------------------------------------------------------------------------
__global__ __launch_bounds__(256, 2)
void vlstm_fused_legacy(const float* __restrict__ xin, const float* __restrict__ h_tm1,
                        const float* __restrict__ c_tm1, const float* __restrict__ z_tm1,
                        const float* __restrict__ Wk, const float* __restrict__ Wr,
                        const float* __restrict__ Wl, const float* __restrict__ bias,
                        float* __restrict__ out)
{
    __shared__ __align__(16) unsigned short Alds[2][128][40];
    __shared__ __align__(16) unsigned short Blds[2][256][40];

    const int tid  = threadIdx.x;
    const int wave = tid >> 6, lane = tid & 63;
    const int wr = wave >> 1, wc = wave & 1;
    const int l15 = lane & 15, q = lane >> 4;

    const int bid = (int)blockIdx.x;
    const int swz = (bid & 7) * 128 + (bid >> 3);
    const int bm = swz >> 5, bn = swz & 31;
    const int row0 = bm * 128, col0 = bn * 64;

    const int arow = tid >> 1, kh = tid & 1;
    const long bg_off = (long)(tid >> 6) * 2048 + col0 + (tid & 63);

    f32x4 acc[4][4][2];
    #pragma unroll
    for (int g = 0; g < 4; ++g)
        #pragma unroll
        for (int mi = 0; mi < 4; ++mi)
            #pragma unroll
            for (int ni = 0; ni < 2; ++ni)
                acc[g][mi][ni] = (f32x4){0.f, 0.f, 0.f, 0.f};

    f32x4 sa[4];
    float sb[32];

#define DO_LOADS_L(kn_) do {                                                    \
    const int s_  = (kn_) >> 6;                                                 \
    const int kl_ = ((kn_) & 63) << 5;                                          \
    const float* Ap_ = (s_ == 0) ? xin : (s_ == 1) ? h_tm1 : z_tm1;             \
    const float* Bp_ = (s_ == 0) ? Wk  : (s_ == 1) ? Wr    : Wl;                \
    const float* ap_ = Ap_ + (long)(row0 + arow) * 2048 + kl_ + kh * 16;        \
    _Pragma("unroll")                                                           \
    for (int i_ = 0; i_ < 4; ++i_) sa[i_] = ((const f32x4*)ap_)[i_];            \
    const float* bp_ = Bp_ + (long)kl_ * 8192 + bg_off;                         \
    _Pragma("unroll")                                                           \
    for (int kk_ = 0; kk_ < 32; ++kk_) sb[kk_] = bp_[(long)kk_ * 8192];         \
} while (0)

#define DO_STORE_L(buf_) do {                                                   \
    short8 p0_, p1_;                                                            \
    _Pragma("unroll")                                                           \
    for (int j_ = 0; j_ < 4; ++j_) {                                            \
        p0_[j_] = f2b(sa[0][j_]); p0_[4 + j_] = f2b(sa[1][j_]);                 \
        p1_[j_] = f2b(sa[2][j_]); p1_[4 + j_] = f2b(sa[3][j_]);                 \
    }                                                                           \
    *(short8*)&Alds[buf_][arow][kh * 16]     = p0_;                             \
    *(short8*)&Alds[buf_][arow][kh * 16 + 8] = p1_;                             \
    _Pragma("unroll")                                                           \
    for (int ks_ = 0; ks_ < 4; ++ks_) {                                         \
        short8 pb_;                                                             \
        _Pragma("unroll")                                                       \
        for (int j_ = 0; j_ < 8; ++j_) pb_[j_] = f2b(sb[ks_ * 8 + j_]);         \
        *(short8*)&Blds[buf_][tid][ks_ * 8] = pb_;                              \
    }                                                                           \
} while (0)

    DO_LOADS_L(0);
    DO_STORE_L(0);
    __syncthreads();

    for (int kt = 0; kt < 192; ++kt) {
        const int cur = kt & 1;
        if (kt + 1 < 192) DO_LOADS_L(kt + 1);

        short8 afr[4];
        #pragma unroll
        for (int mi = 0; mi < 4; ++mi)
            afr[mi] = *(const short8*)&Alds[cur][wr * 64 + mi * 16 + l15][q * 8];

        short8 bfr[4][2];
        #pragma unroll
        for (int g = 0; g < 4; ++g)
            #pragma unroll
            for (int ni = 0; ni < 2; ++ni)
                bfr[g][ni] = *(const short8*)
                    &Blds[cur][g * 64 + wc * 32 + ni * 16 + l15][q * 8];

        #pragma unroll
        for (int g = 0; g < 4; ++g)
            #pragma unroll
            for (int ni = 0; ni < 2; ++ni)
                #pragma unroll
                for (int mi = 0; mi < 4; ++mi)
                    acc[g][mi][ni] = __builtin_amdgcn_mfma_f32_16x16x32_bf16(
                        afr[mi], bfr[g][ni], acc[g][mi][ni], 0, 0, 0);

        if (kt + 1 < 192) DO_STORE_L(cur ^ 1);
        __syncthreads();
    }

#undef DO_LOADS_L
#undef DO_STORE_L

    #pragma unroll
    for (int ni = 0; ni < 2; ++ni) {
        const int col = col0 + wc * 32 + ni * 16 + l15;
        const float bi  = bias[col];
        const float bf_ = bias[2048 + col];
        const float bc  = bias[4096 + col];
        const float bo  = bias[6144 + col];
        #pragma unroll
        for (int mi = 0; mi < 4; ++mi) {
            const int rbase = row0 + wr * 64 + mi * 16 + q * 4;
            #pragma unroll
            for (int rr = 0; rr < 4; ++rr) {
                const int row = rbase + rr;
                const float xi = acc[0][mi][ni][rr] + bi;
                const float xf = acc[1][mi][ni][rr] + bf_;
                const float xc = acc[2][mi][ni][rr] + bc;
                const float xo = acc[3][mi][ni][rr] + bo;
                const float ig = __builtin_amdgcn_fmed3f(0.2f * xi + 0.5f, 0.f, 1.f);
                const float fg = __builtin_amdgcn_fmed3f(0.2f * xf + 0.5f, 0.f, 1.f);
                const float og = __builtin_amdgcn_fmed3f(0.2f * xo + 0.5f, 0.f, 1.f);
                const float cp = c_tm1[(long)row * 2048 + col];
                const float cc = fg * cp + ig * tanhf(xc);
                out[(long)row * 2048 + col] = og * tanhf(cc);
            }
        }
    }
}

extern "C" void kernel_launch(void* const* d_in, const int* in_sizes, int n_in,
                              void* d_out, int out_size, void* d_ws, size_t ws_size,
                              hipStream_t stream) {
    const float* xin  = (const float*)d_in[0];
    const float* h1   = (const float*)d_in[1];
    const float* c1   = (const float*)d_in[2];
    const float* z1   = (const float*)d_in[3];
    const float* Wk   = (const float*)d_in[4];
    const float* Wr   = (const float*)d_in[5];
    const float* Wl   = (const float*)d_in[6];
    const float* bias = (const float*)d_in[7];
    float* out = (float*)d_out;
    (void)in_sizes; (void)n_in; (void)out_size;

    const size_t a_elems = (size_t)4096 * 6144;
    const size_t b_elems = (size_t)8192 * 6144;
    const size_t need = (a_elems + b_elems) * 2;       // ~151 MB

    if (ws_size >= need) {
        unsigned short* Aws = (unsigned short*)d_ws;
        unsigned short* Bws = Aws + a_elems;
        conv_a<<<dim3(12288), dim3(256), 0, stream>>>(xin, h1, z1, Aws);
        conv_b<<<dim3(12288), dim3(256), 0, stream>>>(Wk, Wr, Wl, Bws);
        // grid: 16 m-blocks x 32 hcol-blocks = 512
        vlstm_gemm256<<<dim3(512), dim3(512), 0, stream>>>(Aws, Bws, c1, bias, out);
    } else {
        vlstm_fused_legacy<<<dim3(1024), dim3(256), 0, stream>>>(
            xin, h1, c1, z1, Wk, Wr, Wl, bias, out);
    }
}

// Round 14
// 494.999 us; speedup vs baseline: 2.1300x; 1.0053x over previous
//
#include <hip/hip_runtime.h>
#include <hip/hip_bf16.h>

typedef float f32x4 __attribute__((ext_vector_type(4)));
typedef short short8 __attribute__((ext_vector_type(8)));   // 8 bf16 = 16 B
typedef short short4v __attribute__((ext_vector_type(4)));  // 4 bf16 = 8 B

__device__ __forceinline__ short f2b(float x) {
    union { __hip_bfloat16 b; short s; } u;
    u.b = __float2bfloat16(x);   // round-to-nearest-even
    return u.s;
}

// async global->LDS, 16 B per lane; LDS dest is wave-uniform base + lane*16.
__device__ __forceinline__ void gload16(const void* g, void* l) {
    __builtin_amdgcn_global_load_lds(
        (const __attribute__((address_space(1))) unsigned int*)g,
        (__attribute__((address_space(3))) unsigned int*)l, 16, 0, 0);
}

// ---------------------------------------------------------------------------
// Converter 1: A sources fp32 -> Aws[row][kglob] bf16 (kglob = s*2048+k).
// ---------------------------------------------------------------------------
__global__ __launch_bounds__(256)
void conv_a(const float* __restrict__ x0, const float* __restrict__ x1,
            const float* __restrict__ x2, unsigned short* __restrict__ Aws)
{
    const long i = (long)blockIdx.x * 256 + threadIdx.x;   // unit = 8 elems
    const long per_src = (long)4096 * 2048 / 8;
    const int  s = (int)(i / per_src);
    const long e0 = (i % per_src) * 8;
    const int  row = (int)(e0 >> 11), kl = (int)(e0 & 2047);
    const float* src = (s == 0) ? x0 : (s == 1) ? x1 : x2;
    const f32x4 v0 = *(const f32x4*)(src + e0);
    const f32x4 v1 = *(const f32x4*)(src + e0 + 4);
    short8 p;
    #pragma unroll
    for (int j = 0; j < 4; ++j) { p[j] = f2b(v0[j]); p[4 + j] = f2b(v1[j]); }
    *(short8*)&Aws[(long)row * 6144 + s * 2048 + kl] = p;
}

// ---------------------------------------------------------------------------
// Converter 2: weights fp32 -> Bws[effcol][kglob] bf16 (transposed),
// effcol = gate*2048 + hcol.
// ---------------------------------------------------------------------------
__global__ __launch_bounds__(256)
void conv_b(const float* __restrict__ Wk, const float* __restrict__ Wr,
            const float* __restrict__ Wl, unsigned short* __restrict__ Bws)
{
    __shared__ float lt[64][65];
    const int bid = (int)blockIdx.x;
    const int s   = bid >> 12;
    const int r   = bid & 4095;
    const int kbase = (r >> 7) * 64;
    const int ebase = (r & 127) * 64;
    const float* W = (s == 0) ? Wk : (s == 1) ? Wr : Wl;
    const int tr = threadIdx.x >> 4, tc = threadIdx.x & 15;

    #pragma unroll
    for (int p = 0; p < 4; ++p) {
        const int kr = p * 16 + tr;
        const f32x4 v = *(const f32x4*)&W[(long)(kbase + kr) * 8192 + ebase + tc * 4];
        #pragma unroll
        for (int j = 0; j < 4; ++j) lt[kr][tc * 4 + j] = v[j];
    }
    __syncthreads();
    #pragma unroll
    for (int p = 0; p < 4; ++p) {
        const int er = p * 16 + tr;
        const int k4 = tc * 4;
        short4v qv;
        #pragma unroll
        for (int j = 0; j < 4; ++j) qv[j] = f2b(lt[k4 + j][er]);
        *(short4v*)&Bws[(long)(ebase + er) * 6144 + (long)s * 2048 + kbase + k4] = qv;
    }
}

// ---------------------------------------------------------------------------
// 256x256eff GEMM, free-slip schedule (round-9 structure). Single change vs
// R13: loop-body barriers are BARE s_barrier (no sched_barrier pins), so the
// compiler may sink the tile's trailing register-only MFMA clusters past the
// boundary and interleave them with the next tile's ds_reads (m201 uses bare
// s_barrier). Safety: the vmcnt asm's "memory" clobber still pins ALL memory
// ops at the boundary, so no ds_read can hoist above the DMA-visibility
// point; MFMA sinking is register-dep-safe. Accumulation order unchanged ->
// absmax 1.733e-2 expected exactly (race canary).
// ---------------------------------------------------------------------------
__global__ __launch_bounds__(512, 2)
void vlstm_gemm256(const unsigned short* __restrict__ Aws,
                   const unsigned short* __restrict__ Bws,
                   const float* __restrict__ c_tm1,
                   const float* __restrict__ bias,
                   float* __restrict__ out)
{
    __shared__ __align__(16) unsigned short As[2][256][64];   // 64 KB
    __shared__ __align__(16) unsigned short Bs[3][256][64];   // 96 KB

    const int tid  = threadIdx.x;
    const int w    = tid >> 6, lane = tid & 63;
    const int wm   = w >> 2,  wn   = w & 3;     // 2 x 4 wave grid
    const int l15  = lane & 15, q = lane >> 4;
    const int lrow = lane >> 3;                 // staging: row within 8-row chunk
    const int lsw  = (lane & 7) ^ lrow;         // staging: swizzled source octet
    const int oq   = q ^ (l15 & 7);             // read: swizzled octet base

    const int bid = (int)blockIdx.x;
    const int swz = (bid & 7) * 64 + (bid >> 3);    // XCD-bijective (512 % 8 == 0)
    const int bm  = swz >> 5, bn = swz & 31;        // 16 x 32
    const int row0 = bm * 256, c0 = bn * 64;        // c0 in hcols

    const long a_base = (long)(row0 + w * 16 + lrow) * 6144 + lsw * 8;

    f32x4 acc[8][4];            // [mi 0..7][gate]
    #pragma unroll
    for (int mi = 0; mi < 8; ++mi)
        #pragma unroll
        for (int g = 0; g < 4; ++g)
            acc[mi][g] = (f32x4){0.f, 0.f, 0.f, 0.f};

    short8 afr[4][2];           // current mh-half: [mi_][kh]
    short8 bfr[4][2];           // all 4 gates resident: [ni][kh]

#define STAGE_A(buf_, t_, h_) do { _Pragma("unroll")                             \
    for (int j_ = 0; j_ < 2; ++j_)                                               \
        gload16(Aws + a_base + (long)((h_) * 128 + j_ * 8) * 6144                \
                    + (long)(t_) * 64,                                           \
                &As[buf_][(h_) * 128 + w * 16 + j_ * 8][0]); } while (0)

#define STAGE_B(buf_, t_, h_) do { _Pragma("unroll")                             \
    for (int j_ = 0; j_ < 2; ++j_) {                                             \
        const int e0_ = (h_) * 128 + w * 16 + j_ * 8;                            \
        const int grow_ = ((e0_ >> 4) & 3) * 2048 + c0 + (e0_ >> 6) * 16         \
                          + (e0_ & 8) + lrow;                                    \
        gload16(Bws + (long)grow_ * 6144 + lsw * 8 + (long)(t_) * 64,            \
                &Bs[buf_][e0_][0]); } } while (0)

#define LOAD_AFR(cur_, mh_) do { _Pragma("unroll")                               \
    for (int mi_ = 0; mi_ < 4; ++mi_) { _Pragma("unroll")                        \
        for (int kh_ = 0; kh_ < 2; ++kh_)                                        \
            afr[mi_][kh_] = *(const short8*)                                     \
                &As[cur_][wm * 128 + (mh_) * 64 + mi_ * 16 + l15]                \
                         [(oq ^ (kh_ << 2)) * 8]; } } while (0)

#define LOAD_BFR(cur_, nlo_) do { _Pragma("unroll")                              \
    for (int g_ = 0; g_ < 2; ++g_) { _Pragma("unroll")                           \
        for (int kh_ = 0; kh_ < 2; ++kh_)                                        \
            bfr[(nlo_) + g_][kh_] = *(const short8*)                             \
                &Bs[cur_][wn * 64 + ((nlo_) + g_) * 16 + l15]                    \
                         [(oq ^ (kh_ << 2)) * 8]; } } while (0)

#define MFMA_Q(mh_, nlo_) do {                                                   \
    __builtin_amdgcn_s_setprio(1);                                               \
    _Pragma("unroll")                                                            \
    for (int kh_ = 0; kh_ < 2; ++kh_) { _Pragma("unroll")                        \
        for (int mi_ = 0; mi_ < 4; ++mi_) { _Pragma("unroll")                    \
            for (int g_ = 0; g_ < 2; ++g_)                                       \
                acc[(mh_) * 4 + mi_][(nlo_) + g_] =                              \
                    __builtin_amdgcn_mfma_f32_16x16x32_bf16(                     \
                        afr[mi_][kh_], bfr[(nlo_) + g_][kh_],                    \
                        acc[(mh_) * 4 + mi_][(nlo_) + g_], 0, 0, 0); } }         \
    __builtin_amdgcn_s_setprio(0); } while (0)

// prologue-only pinned barrier (rule 18/21)
#define BARRIER_PINNED() do { __builtin_amdgcn_sched_barrier(0);                 \
    __builtin_amdgcn_s_barrier();                                                \
    __builtin_amdgcn_sched_barrier(0); } while (0)

    // Prologue: stage A(0)->bufA0, B(0)->bufB0, B(1)->bufB1.
    // vmcnt(4): A(0)+B(0) (oldest 8) arrived; B(1) (4) stays in flight.
    STAGE_A(0, 0, 0); STAGE_A(0, 0, 1);
    STAGE_B(0, 0, 0); STAGE_B(0, 0, 1);
    STAGE_B(1, 1, 0); STAGE_B(1, 1, 1);
    asm volatile("s_waitcnt vmcnt(4)" ::: "memory");
    BARRIER_PINNED();

    int bB = 0;   // t % 3, maintained incrementally (wave-uniform)
    for (int t = 0; t < 96; ++t) {
        const int bA = t & 1, bAn = bA ^ 1;
        const int bBs = bB ? bB - 1 : 2;        // (t+2) % 3
        // free-slip tile body: no intra-tile barriers.
        LOAD_AFR(bA, 0);
        LOAD_BFR(bB, 0);
        if (t + 1 < 96) STAGE_A(bAn, t + 1, 0);
        MFMA_Q(0, 0);
        LOAD_BFR(bB, 2);
        if (t + 1 < 96) STAGE_A(bAn, t + 1, 1);
        MFMA_Q(0, 2);
        LOAD_AFR(bA, 1);
        if (t + 2 < 96) STAGE_B(bBs, t + 2, 0);
        MFMA_Q(1, 0);
        if (t + 2 < 96) STAGE_B(bBs, t + 2, 1);
        MFMA_Q(1, 2);
        // boundary: counted vmcnt (memory clobber pins all memory ops here);
        // BARE s_barrier lets register-only MFMAs sink across for overlap.
        if (t < 94) asm volatile("s_waitcnt vmcnt(4)" ::: "memory");
        else        asm volatile("s_waitcnt vmcnt(0)" ::: "memory");
        __builtin_amdgcn_s_barrier();
        bB = (bB == 2) ? 0 : bB + 1;
    }

#undef STAGE_A
#undef STAGE_B
#undef LOAD_AFR
#undef LOAD_BFR
#undef MFMA_Q
#undef BARRIER_PINNED

    // Epilogue: C/D layout col = l15, row = q*4 + rr (m89/m91 HW-verified).
    {
        const int col = c0 + wn * 16 + l15;
        const float bi  = bias[col];
        const float bf_ = bias[2048 + col];
        const float bc  = bias[4096 + col];
        const float bo  = bias[6144 + col];
        #pragma unroll
        for (int mi = 0; mi < 8; ++mi) {
            const int rbase = row0 + wm * 128 + mi * 16 + q * 4;
            #pragma unroll
            for (int rr = 0; rr < 4; ++rr) {
                const int row = rbase + rr;
                const float xi = acc[mi][0][rr] + bi;
                const float xf = acc[mi][1][rr] + bf_;
                const float xc = acc[mi][2][rr] + bc;
                const float xo = acc[mi][3][rr] + bo;
                const float ig = __builtin_amdgcn_fmed3f(0.2f * xi + 0.5f, 0.f, 1.f);
                const float fg = __builtin_amdgcn_fmed3f(0.2f * xf + 0.5f, 0.f, 1.f);
                const float og = __builtin_amdgcn_fmed3f(0.2f * xo + 0.5f, 0.f, 1.f);
                const float cp = c_tm1[(long)row * 2048 + col];
                const float cc = fg * cp + ig * tanhf(xc);
                out[(long)row * 2048 + col] = og * tanhf(cc);
            }
        }
    }
}

// ---------------------------------------------------------------------------
// Legacy fallback (round-4 kernel, verbatim): only if ws_size is too small.
// ---------------------------------------------------------------------------
__global__ __launch_bounds__(256, 2)
void vlstm_fused_legacy(const float* __restrict__ xin, const float* __restrict__ h_tm1,
                        const float* __restrict__ c_tm1, const float* __restrict__ z_tm1,
                        const float* __restrict__ Wk, const float* __restrict__ Wr,
                        const float* __restrict__ Wl, const float* __restrict__ bias,
                        float* __restrict__ out)
{
    __shared__ __align__(16) unsigned short Alds[2][128][40];
    __shared__ __align__(16) unsigned short Blds[2][256][40];

    const int tid  = threadIdx.x;
    const int wave = tid >> 6, lane = tid & 63;
    const int wr = wave >> 1, wc = wave & 1;
    const int l15 = lane & 15, q = lane >> 4;

    const int bid = (int)blockIdx.x;
    const int swz = (bid & 7) * 128 + (bid >> 3);
    const int bm = swz >> 5, bn = swz & 31;
    const int row0 = bm * 128, col0 = bn * 64;

    const int arow = tid >> 1, kh = tid & 1;
    const long bg_off = (long)(tid >> 6) * 2048 + col0 + (tid & 63);

    f32x4 acc[4][4][2];
    #pragma unroll
    for (int g = 0; g < 4; ++g)
        #pragma unroll
        for (int mi = 0; mi < 4; ++mi)
            #pragma unroll
            for (int ni = 0; ni < 2; ++ni)
                acc[g][mi][ni] = (f32x4){0.f, 0.f, 0.f, 0.f};

    f32x4 sa[4];
    float sb[32];

#define DO_LOADS_L(kn_) do {                                                    \
    const int s_  = (kn_) >> 6;                                                 \
    const int kl_ = ((kn_) & 63) << 5;                                          \
    const float* Ap_ = (s_ == 0) ? xin : (s_ == 1) ? h_tm1 : z_tm1;             \
    const float* Bp_ = (s_ == 0) ? Wk  : (s_ == 1) ? Wr    : Wl;                \
    const float* ap_ = Ap_ + (long)(row0 + arow) * 2048 + kl_ + kh * 16;        \
    _Pragma("unroll")                                                           \
    for (int i_ = 0; i_ < 4; ++i_) sa[i_] = ((const f32x4*)ap_)[i_];            \
    const float* bp_ = Bp_ + (long)kl_ * 8192 + bg_off;                         \
    _Pragma("unroll")                                                           \
    for (int kk_ = 0; kk_ < 32; ++kk_) sb[kk_] = bp_[(long)kk_ * 8192];         \
} while (0)

#define DO_STORE_L(buf_) do {                                                   \
    short8 p0_, p1_;                                                            \
    _Pragma("unroll")                                                           \
    for (int j_ = 0; j_ < 4; ++j_) {                                            \
        p0_[j_] = f2b(sa[0][j_]); p0_[4 + j_] = f2b(sa[1][j_]);                 \
        p1_[j_] = f2b(sa[2][j_]); p1_[4 + j_] = f2b(sa[3][j_]);                 \
    }                                                                           \
    *(short8*)&Alds[buf_][arow][kh * 16]     = p0_;                             \
    *(short8*)&Alds[buf_][arow][kh * 16 + 8] = p1_;                             \
    _Pragma("unroll")                                                           \
    for (int ks_ = 0; ks_ < 4; ++ks_) {                                         \
        short8 pb_;                                                             \
        _Pragma("unroll")                                                       \
        for (int j_ = 0; j_ < 8; ++j_) pb_[j_] = f2b(sb[ks_ * 8 + j_]);         \
        *(short8*)&Blds[buf_][tid][ks_ * 8] = pb_;                              \
    }                                                                           \
} while (0)

    DO_LOADS_L(0);
    DO_STORE_L(0);
    __syncthreads();

    for (int kt = 0; kt < 192; ++kt) {
        const int cur = kt & 1;
        if (kt + 1 < 192) DO_LOADS_L(kt + 1);

        short8 afr[4];
        #pragma unroll
        for (int mi = 0; mi < 4; ++mi)
            afr[mi] = *(const short8*)&Alds[cur][wr * 64 + mi * 16 + l15][q * 8];

        short8 bfr[4][2];
        #pragma unroll
        for (int g = 0; g < 4; ++g)
            #pragma unroll
            for (int ni = 0; ni < 2; ++ni)
                bfr[g][ni] = *(const short8*)
                    &Blds[cur][g * 64 + wc * 32 + ni * 16 + l15][q * 8];

        #pragma unroll
        for (int g = 0; g < 4; ++g)
            #pragma unroll
            for (int ni = 0; ni < 2; ++ni)
                #pragma unroll
                for (int mi = 0; mi < 4; ++mi)
                    acc[g][mi][ni] = __builtin_amdgcn_mfma_f32_16x16x32_bf16(
                        afr[mi], bfr[g][ni], acc[g][mi][ni], 0, 0, 0);

        if (kt + 1 < 192) DO_STORE_L(cur ^ 1);
        __syncthreads();
    }

#undef DO_LOADS_L
#undef DO_STORE_L

    #pragma unroll
    for (int ni = 0; ni < 2; ++ni) {
        const int col = col0 + wc * 32 + ni * 16 + l15;
        const float bi  = bias[col];
        const float bf_ = bias[2048 + col];
        const float bc  = bias[4096 + col];
        const float bo  = bias[6144 + col];
        #pragma unroll
        for (int mi = 0; mi < 4; ++mi) {
            const int rbase = row0 + wr * 64 + mi * 16 + q * 4;
            #pragma unroll
            for (int rr = 0; rr < 4; ++rr) {
                const int row = rbase + rr;
                const float xi = acc[0][mi][ni][rr] + bi;
                const float xf = acc[1][mi][ni][rr] + bf_;
                const float xc = acc[2][mi][ni][rr] + bc;
                const float xo = acc[3][mi][ni][rr] + bo;
                const float ig = __builtin_amdgcn_fmed3f(0.2f * xi + 0.5f, 0.f, 1.f);
                const float fg = __builtin_amdgcn_fmed3f(0.2f * xf + 0.5f, 0.f, 1.f);
                const float og = __builtin_amdgcn_fmed3f(0.2f * xo + 0.5f, 0.f, 1.f);
                const float cp = c_tm1[(long)row * 2048 + col];
                const float cc = fg * cp + ig * tanhf(xc);
                out[(long)row * 2048 + col] = og * tanhf(cc);
            }
        }
    }
}

extern "C" void kernel_launch(void* const* d_in, const int* in_sizes, int n_in,
                              void* d_out, int out_size, void* d_ws, size_t ws_size,
                              hipStream_t stream) {
    const float* xin  = (const float*)d_in[0];
    const float* h1   = (const float*)d_in[1];
    const float* c1   = (const float*)d_in[2];
    const float* z1   = (const float*)d_in[3];
    const float* Wk   = (const float*)d_in[4];
    const float* Wr   = (const float*)d_in[5];
    const float* Wl   = (const float*)d_in[6];
    const float* bias = (const float*)d_in[7];
    float* out = (float*)d_out;
    (void)in_sizes; (void)n_in; (void)out_size;

    const size_t a_elems = (size_t)4096 * 6144;
    const size_t b_elems = (size_t)8192 * 6144;
    const size_t need = (a_elems + b_elems) * 2;       // ~151 MB

    if (ws_size >= need) {
        unsigned short* Aws = (unsigned short*)d_ws;
        unsigned short* Bws = Aws + a_elems;
        conv_a<<<dim3(12288), dim3(256), 0, stream>>>(xin, h1, z1, Aws);
        conv_b<<<dim3(12288), dim3(256), 0, stream>>>(Wk, Wr, Wl, Bws);
        // grid: 16 m-blocks x 32 hcol-blocks = 512
        vlstm_gemm256<<<dim3(512), dim3(512), 0, stream>>>(Aws, Bws, c1, bias, out);
    } else {
        vlstm_fused_legacy<<<dim3(1024), dim3(256), 0, stream>>>(
            xin, h1, c1, z1, Wk, Wr, Wl, bias, out);
    }
}

// Round 15
// 493.335 us; speedup vs baseline: 2.1372x; 1.0034x over previous
//
#include <hip/hip_runtime.h>
#include <hip/hip_bf16.h>

typedef float f32x4 __attribute__((ext_vector_type(4)));
typedef short short8 __attribute__((ext_vector_type(8)));   // 8 bf16 = 16 B
typedef short short4v __attribute__((ext_vector_type(4)));  // 4 bf16 = 8 B

__device__ __forceinline__ short f2b(float x) {
    union { __hip_bfloat16 b; short s; } u;
    u.b = __float2bfloat16(x);   // round-to-nearest-even
    return u.s;
}

// async global->LDS, 16 B per lane; LDS dest is wave-uniform base + lane*16.
__device__ __forceinline__ void gload16(const void* g, void* l) {
    __builtin_amdgcn_global_load_lds(
        (const __attribute__((address_space(1))) unsigned int*)g,
        (__attribute__((address_space(3))) unsigned int*)l, 16, 0, 0);
}

// ---------------------------------------------------------------------------
// Merged converter (single launch; removes one inter-kernel gap):
//   blocks [0, 12288):      A sources fp32 -> Aws[row][kglob] bf16
//   blocks [12288, 24576):  weights fp32 -> Bws[effcol][kglob] bf16 (transposed)
// Branch is block-uniform; conv_b path's LDS transpose + __syncthreads is
// reached by all threads of its blocks (and never by conv_a blocks).
// Both compute paths are byte-identical to rounds 5-14's converters.
// ---------------------------------------------------------------------------
__global__ __launch_bounds__(256)
void conv_ab(const float* __restrict__ x0, const float* __restrict__ x1,
             const float* __restrict__ x2, unsigned short* __restrict__ Aws,
             const float* __restrict__ Wk, const float* __restrict__ Wr,
             const float* __restrict__ Wl, unsigned short* __restrict__ Bws)
{
    __shared__ float lt[64][65];
    const int bid0 = (int)blockIdx.x;

    if (bid0 < 12288) {
        // ---- conv_a path ----
        const long i = (long)bid0 * 256 + threadIdx.x;   // unit = 8 elems
        const long per_src = (long)4096 * 2048 / 8;
        const int  s = (int)(i / per_src);
        const long e0 = (i % per_src) * 8;
        const int  row = (int)(e0 >> 11), kl = (int)(e0 & 2047);
        const float* src = (s == 0) ? x0 : (s == 1) ? x1 : x2;
        const f32x4 v0 = *(const f32x4*)(src + e0);
        const f32x4 v1 = *(const f32x4*)(src + e0 + 4);
        short8 p;
        #pragma unroll
        for (int j = 0; j < 4; ++j) { p[j] = f2b(v0[j]); p[4 + j] = f2b(v1[j]); }
        *(short8*)&Aws[(long)row * 6144 + s * 2048 + kl] = p;
        return;
    }

    // ---- conv_b path ----
    const int bid = bid0 - 12288;
    const int s   = bid >> 12;
    const int r   = bid & 4095;
    const int kbase = (r >> 7) * 64;
    const int ebase = (r & 127) * 64;
    const float* W = (s == 0) ? Wk : (s == 1) ? Wr : Wl;
    const int tr = threadIdx.x >> 4, tc = threadIdx.x & 15;

    #pragma unroll
    for (int p = 0; p < 4; ++p) {
        const int kr = p * 16 + tr;
        const f32x4 v = *(const f32x4*)&W[(long)(kbase + kr) * 8192 + ebase + tc * 4];
        #pragma unroll
        for (int j = 0; j < 4; ++j) lt[kr][tc * 4 + j] = v[j];
    }
    __syncthreads();
    #pragma unroll
    for (int p = 0; p < 4; ++p) {
        const int er = p * 16 + tr;
        const int k4 = tc * 4;
        short4v qv;
        #pragma unroll
        for (int j = 0; j < 4; ++j) qv[j] = f2b(lt[k4 + j][er]);
        *(short4v*)&Bws[(long)(ebase + er) * 6144 + (long)s * 2048 + kbase + k4] = qv;
    }
}

// ---------------------------------------------------------------------------
// 256x256eff GEMM, free-slip schedule (round-14 optimum, verbatim):
// ONE bare s_barrier per K-tile (R14 A/B: pinned vs bare = null; bare kept).
// A double-buffered (2x32 KB), B TRIPLE-buffered (3x32 KB): no staging write
// in tile t targets a buffer read in tile t; cross-tile overwrites ordered by
// the boundary barrier. setprio kept (R10 A/B: removing costs 6pt MfmaUtil).
// Counted vmcnt(4) per boundary (vmcnt(0) only t>=94). B in LDS (R11/R12:
// B-direct variants regress -42%/-134%). Structure ceiling: LDS pipe ~2800
// cyc/tile + ds_read latency exposure at the register-forced 2 waves/SIMD
// (acc 128 AGPR + 116 VGPR = 244/256). MFMA order per acc element identical
// to rounds 5-14 -> absmax 1.733e-2 exactly.
// ---------------------------------------------------------------------------
__global__ __launch_bounds__(512, 2)
void vlstm_gemm256(const unsigned short* __restrict__ Aws,
                   const unsigned short* __restrict__ Bws,
                   const float* __restrict__ c_tm1,
                   const float* __restrict__ bias,
                   float* __restrict__ out)
{
    __shared__ __align__(16) unsigned short As[2][256][64];   // 64 KB
    __shared__ __align__(16) unsigned short Bs[3][256][64];   // 96 KB

    const int tid  = threadIdx.x;
    const int w    = tid >> 6, lane = tid & 63;
    const int wm   = w >> 2,  wn   = w & 3;     // 2 x 4 wave grid
    const int l15  = lane & 15, q = lane >> 4;
    const int lrow = lane >> 3;                 // staging: row within 8-row chunk
    const int lsw  = (lane & 7) ^ lrow;         // staging: swizzled source octet
    const int oq   = q ^ (l15 & 7);             // read: swizzled octet base

    const int bid = (int)blockIdx.x;
    const int swz = (bid & 7) * 64 + (bid >> 3);    // XCD-bijective (512 % 8 == 0)
    const int bm  = swz >> 5, bn = swz & 31;        // 16 x 32
    const int row0 = bm * 256, c0 = bn * 64;        // c0 in hcols

    const long a_base = (long)(row0 + w * 16 + lrow) * 6144 + lsw * 8;

    f32x4 acc[8][4];            // [mi 0..7][gate]
    #pragma unroll
    for (int mi = 0; mi < 8; ++mi)
        #pragma unroll
        for (int g = 0; g < 4; ++g)
            acc[mi][g] = (f32x4){0.f, 0.f, 0.f, 0.f};

    short8 afr[4][2];           // current mh-half: [mi_][kh]
    short8 bfr[4][2];           // all 4 gates resident: [ni][kh]

#define STAGE_A(buf_, t_, h_) do { _Pragma("unroll")                             \
    for (int j_ = 0; j_ < 2; ++j_)                                               \
        gload16(Aws + a_base + (long)((h_) * 128 + j_ * 8) * 6144                \
                    + (long)(t_) * 64,                                           \
                &As[buf_][(h_) * 128 + w * 16 + j_ * 8][0]); } while (0)

#define STAGE_B(buf_, t_, h_) do { _Pragma("unroll")                             \
    for (int j_ = 0; j_ < 2; ++j_) {                                             \
        const int e0_ = (h_) * 128 + w * 16 + j_ * 8;                            \
        const int grow_ = ((e0_ >> 4) & 3) * 2048 + c0 + (e0_ >> 6) * 16         \
                          + (e0_ & 8) + lrow;                                    \
        gload16(Bws + (long)grow_ * 6144 + lsw * 8 + (long)(t_) * 64,            \
                &Bs[buf_][e0_][0]); } } while (0)

#define LOAD_AFR(cur_, mh_) do { _Pragma("unroll")                               \
    for (int mi_ = 0; mi_ < 4; ++mi_) { _Pragma("unroll")                        \
        for (int kh_ = 0; kh_ < 2; ++kh_)                                        \
            afr[mi_][kh_] = *(const short8*)                                     \
                &As[cur_][wm * 128 + (mh_) * 64 + mi_ * 16 + l15]                \
                         [(oq ^ (kh_ << 2)) * 8]; } } while (0)

#define LOAD_BFR(cur_, nlo_) do { _Pragma("unroll")                              \
    for (int g_ = 0; g_ < 2; ++g_) { _Pragma("unroll")                           \
        for (int kh_ = 0; kh_ < 2; ++kh_)                                        \
            bfr[(nlo_) + g_][kh_] = *(const short8*)                             \
                &Bs[cur_][wn * 64 + ((nlo_) + g_) * 16 + l15]                    \
                         [(oq ^ (kh_ << 2)) * 8]; } } while (0)

#define MFMA_Q(mh_, nlo_) do {                                                   \
    __builtin_amdgcn_s_setprio(1);                                               \
    _Pragma("unroll")                                                            \
    for (int kh_ = 0; kh_ < 2; ++kh_) { _Pragma("unroll")                        \
        for (int mi_ = 0; mi_ < 4; ++mi_) { _Pragma("unroll")                    \
            for (int g_ = 0; g_ < 2; ++g_)                                       \
                acc[(mh_) * 4 + mi_][(nlo_) + g_] =                              \
                    __builtin_amdgcn_mfma_f32_16x16x32_bf16(                     \
                        afr[mi_][kh_], bfr[(nlo_) + g_][kh_],                    \
                        acc[(mh_) * 4 + mi_][(nlo_) + g_], 0, 0, 0); } }         \
    __builtin_amdgcn_s_setprio(0); } while (0)

// prologue-only pinned barrier (rule 18/21)
#define BARRIER_PINNED() do { __builtin_amdgcn_sched_barrier(0);                 \
    __builtin_amdgcn_s_barrier();                                                \
    __builtin_amdgcn_sched_barrier(0); } while (0)

    // Prologue: stage A(0)->bufA0, B(0)->bufB0, B(1)->bufB1.
    // vmcnt(4): A(0)+B(0) (oldest 8) arrived; B(1) (4) stays in flight.
    STAGE_A(0, 0, 0); STAGE_A(0, 0, 1);
    STAGE_B(0, 0, 0); STAGE_B(0, 0, 1);
    STAGE_B(1, 1, 0); STAGE_B(1, 1, 1);
    asm volatile("s_waitcnt vmcnt(4)" ::: "memory");
    BARRIER_PINNED();

    int bB = 0;   // t % 3, maintained incrementally (wave-uniform)
    for (int t = 0; t < 96; ++t) {
        const int bA = t & 1, bAn = bA ^ 1;
        const int bBs = bB ? bB - 1 : 2;        // (t+2) % 3
        // free-slip tile body: no intra-tile barriers.
        LOAD_AFR(bA, 0);
        LOAD_BFR(bB, 0);
        if (t + 1 < 96) STAGE_A(bAn, t + 1, 0);
        MFMA_Q(0, 0);
        LOAD_BFR(bB, 2);
        if (t + 1 < 96) STAGE_A(bAn, t + 1, 1);
        MFMA_Q(0, 2);
        LOAD_AFR(bA, 1);
        if (t + 2 < 96) STAGE_B(bBs, t + 2, 0);
        MFMA_Q(1, 0);
        if (t + 2 < 96) STAGE_B(bBs, t + 2, 1);
        MFMA_Q(1, 2);
        // boundary: counted vmcnt (memory clobber pins all memory ops here);
        // BARE s_barrier lets register-only MFMAs sink across for overlap.
        if (t < 94) asm volatile("s_waitcnt vmcnt(4)" ::: "memory");
        else        asm volatile("s_waitcnt vmcnt(0)" ::: "memory");
        __builtin_amdgcn_s_barrier();
        bB = (bB == 2) ? 0 : bB + 1;
    }

#undef STAGE_A
#undef STAGE_B
#undef LOAD_AFR
#undef LOAD_BFR
#undef MFMA_Q
#undef BARRIER_PINNED

    // Epilogue: C/D layout col = l15, row = q*4 + rr (m89/m91 HW-verified).
    {
        const int col = c0 + wn * 16 + l15;
        const float bi  = bias[col];
        const float bf_ = bias[2048 + col];
        const float bc  = bias[4096 + col];
        const float bo  = bias[6144 + col];
        #pragma unroll
        for (int mi = 0; mi < 8; ++mi) {
            const int rbase = row0 + wm * 128 + mi * 16 + q * 4;
            #pragma unroll
            for (int rr = 0; rr < 4; ++rr) {
                const int row = rbase + rr;
                const float xi = acc[mi][0][rr] + bi;
                const float xf = acc[mi][1][rr] + bf_;
                const float xc = acc[mi][2][rr] + bc;
                const float xo = acc[mi][3][rr] + bo;
                const float ig = __builtin_amdgcn_fmed3f(0.2f * xi + 0.5f, 0.f, 1.f);
                const float fg = __builtin_amdgcn_fmed3f(0.2f * xf + 0.5f, 0.f, 1.f);
                const float og = __builtin_amdgcn_fmed3f(0.2f * xo + 0.5f, 0.f, 1.f);
                const float cp = c_tm1[(long)row * 2048 + col];
                const float cc = fg * cp + ig * tanhf(xc);
                out[(long)row * 2048 + col] = og * tanhf(cc);
            }
        }
    }
}

// ---------------------------------------------------------------------------
// Legacy fallback (round-4 kernel, verbatim): only if ws_size is too small.
// ---------------------------------------------------------------------------
__global__ __launch_bounds__(256, 2)
void vlstm_fused_legacy(const float* __restrict__ xin, const float* __restrict__ h_tm1,
                        const float* __restrict__ c_tm1, const float* __restrict__ z_tm1,
                        const float* __restrict__ Wk, const float* __restrict__ Wr,
                        const float* __restrict__ Wl, const float* __restrict__ bias,
                        float* __restrict__ out)
{
    __shared__ __align__(16) unsigned short Alds[2][128][40];
    __shared__ __align__(16) unsigned short Blds[2][256][40];

    const int tid  = threadIdx.x;
    const int wave = tid >> 6, lane = tid & 63;
    const int wr = wave >> 1, wc = wave & 1;
    const int l15 = lane & 15, q = lane >> 4;

    const int bid = (int)blockIdx.x;
    const int swz = (bid & 7) * 128 + (bid >> 3);
    const int bm = swz >> 5, bn = swz & 31;
    const int row0 = bm * 128, col0 = bn * 64;

    const int arow = tid >> 1, kh = tid & 1;
    const long bg_off = (long)(tid >> 6) * 2048 + col0 + (tid & 63);

    f32x4 acc[4][4][2];
    #pragma unroll
    for (int g = 0; g < 4; ++g)
        #pragma unroll
        for (int mi = 0; mi < 4; ++mi)
            #pragma unroll
            for (int ni = 0; ni < 2; ++ni)
                acc[g][mi][ni] = (f32x4){0.f, 0.f, 0.f, 0.f};

    f32x4 sa[4];
    float sb[32];

#define DO_LOADS_L(kn_) do {                                                    \
    const int s_  = (kn_) >> 6;                                                 \
    const int kl_ = ((kn_) & 63) << 5;                                          \
    const float* Ap_ = (s_ == 0) ? xin : (s_ == 1) ? h_tm1 : z_tm1;             \
    const float* Bp_ = (s_ == 0) ? Wk  : (s_ == 1) ? Wr    : Wl;                \
    const float* ap_ = Ap_ + (long)(row0 + arow) * 2048 + kl_ + kh * 16;        \
    _Pragma("unroll")                                                           \
    for (int i_ = 0; i_ < 4; ++i_) sa[i_] = ((const f32x4*)ap_)[i_];            \
    const float* bp_ = Bp_ + (long)kl_ * 8192 + bg_off;                         \
    _Pragma("unroll")                                                           \
    for (int kk_ = 0; kk_ < 32; ++kk_) sb[kk_] = bp_[(long)kk_ * 8192];         \
} while (0)

#define DO_STORE_L(buf_) do {                                                   \
    short8 p0_, p1_;                                                            \
    _Pragma("unroll")                                                           \
    for (int j_ = 0; j_ < 4; ++j_) {                                            \
        p0_[j_] = f2b(sa[0][j_]); p0_[4 + j_] = f2b(sa[1][j_]);                 \
        p1_[j_] = f2b(sa[2][j_]); p1_[4 + j_] = f2b(sa[3][j_]);                 \
    }                                                                           \
    *(short8*)&Alds[buf_][arow][kh * 16]     = p0_;                             \
    *(short8*)&Alds[buf_][arow][kh * 16 + 8] = p1_;                             \
    _Pragma("unroll")                                                           \
    for (int ks_ = 0; ks_ < 4; ++ks_) {                                         \
        short8 pb_;                                                             \
        _Pragma("unroll")                                                       \
        for (int j_ = 0; j_ < 8; ++j_) pb_[j_] = f2b(sb[ks_ * 8 + j_]);         \
        *(short8*)&Blds[buf_][tid][ks_ * 8] = pb_;                              \
    }                                                                           \
} while (0)

    DO_LOADS_L(0);
    DO_STORE_L(0);
    __syncthreads();

    for (int kt = 0; kt < 192; ++kt) {
        const int cur = kt & 1;
        if (kt + 1 < 192) DO_LOADS_L(kt + 1);

        short8 afr[4];
        #pragma unroll
        for (int mi = 0; mi < 4; ++mi)
            afr[mi] = *(const short8*)&Alds[cur][wr * 64 + mi * 16 + l15][q * 8];

        short8 bfr[4][2];
        #pragma unroll
        for (int g = 0; g < 4; ++g)
            #pragma unroll
            for (int ni = 0; ni < 2; ++ni)
                bfr[g][ni] = *(const short8*)
                    &Blds[cur][g * 64 + wc * 32 + ni * 16 + l15][q * 8];

        #pragma unroll
        for (int g = 0; g < 4; ++g)
            #pragma unroll
            for (int ni = 0; ni < 2; ++ni)
                #pragma unroll
                for (int mi = 0; mi < 4; ++mi)
                    acc[g][mi][ni] = __builtin_amdgcn_mfma_f32_16x16x32_bf16(
                        afr[mi], bfr[g][ni], acc[g][mi][ni], 0, 0, 0);

        if (kt + 1 < 192) DO_STORE_L(cur ^ 1);
        __syncthreads();
    }

#undef DO_LOADS_L
#undef DO_STORE_L

    #pragma unroll
    for (int ni = 0; ni < 2; ++ni) {
        const int col = col0 + wc * 32 + ni * 16 + l15;
        const float bi  = bias[col];
        const float bf_ = bias[2048 + col];
        const float bc  = bias[4096 + col];
        const float bo  = bias[6144 + col];
        #pragma unroll
        for (int mi = 0; mi < 4; ++mi) {
            const int rbase = row0 + wr * 64 + mi * 16 + q * 4;
            #pragma unroll
            for (int rr = 0; rr < 4; ++rr) {
                const int row = rbase + rr;
                const float xi = acc[0][mi][ni][rr] + bi;
                const float xf = acc[1][mi][ni][rr] + bf_;
                const float xc = acc[2][mi][ni][rr] + bc;
                const float xo = acc[3][mi][ni][rr] + bo;
                const float ig = __builtin_amdgcn_fmed3f(0.2f * xi + 0.5f, 0.f, 1.f);
                const float fg = __builtin_amdgcn_fmed3f(0.2f * xf + 0.5f, 0.f, 1.f);
                const float og = __builtin_amdgcn_fmed3f(0.2f * xo + 0.5f, 0.f, 1.f);
                const float cp = c_tm1[(long)row * 2048 + col];
                const float cc = fg * cp + ig * tanhf(xc);
                out[(long)row * 2048 + col] = og * tanhf(cc);
            }
        }
    }
}

extern "C" void kernel_launch(void* const* d_in, const int* in_sizes, int n_in,
                              void* d_out, int out_size, void* d_ws, size_t ws_size,
                              hipStream_t stream) {
    const float* xin  = (const float*)d_in[0];
    const float* h1   = (const float*)d_in[1];
    const float* c1   = (const float*)d_in[2];
    const float* z1   = (const float*)d_in[3];
    const float* Wk   = (const float*)d_in[4];
    const float* Wr   = (const float*)d_in[5];
    const float* Wl   = (const float*)d_in[6];
    const float* bias = (const float*)d_in[7];
    float* out = (float*)d_out;
    (void)in_sizes; (void)n_in; (void)out_size;

    const size_t a_elems = (size_t)4096 * 6144;
    const size_t b_elems = (size_t)8192 * 6144;
    const size_t need = (a_elems + b_elems) * 2;       // ~151 MB

    if (ws_size >= need) {
        unsigned short* Aws = (unsigned short*)d_ws;
        unsigned short* Bws = Aws + a_elems;
        // merged converter: one launch (A-blocks 0..12287, B-blocks 12288..24575)
        conv_ab<<<dim3(24576), dim3(256), 0, stream>>>(xin, h1, z1, Aws,
                                                       Wk, Wr, Wl, Bws);
        // grid: 16 m-blocks x 32 hcol-blocks = 512
        vlstm_gemm256<<<dim3(512), dim3(512), 0, stream>>>(Aws, Bws, c1, bias, out);
    } else {
        vlstm_fused_legacy<<<dim3(1024), dim3(256), 0, stream>>>(
            xin, h1, c1, z1, Wk, Wr, Wl, bias, out);
    }
}